// Round 16
// baseline (1093.860 us; speedup 1.0000x reference)
//
#include <hip/hip_runtime.h>
#include <hip/hip_bf16.h>

#define N_NODES 50000
#define N_EDGES 800000
#define LATENT 32
#define STEPS 10
#define NEG_SLOPE 0.01f
#define LN_EPS 1e-5f
#define N_TILES (N_EDGES / 16)
#define TPW 4                 // tiles per wave (3125 blocks * 4 waves * 4 tiles = 50000)
#define TILES_PER_BLOCK 16    // 4 waves * TPW
#define SCAN_BLK 256
#define SCAN_NBLK ((N_NODES + SCAN_BLK - 1) / SCAN_BLK)  // 196
#define STG_STRIDE 36         // 16-row staging, +4 pad: 16B-aligned rows, 2-way banks

typedef __attribute__((ext_vector_type(8))) __bf16 bf16x8;
typedef __attribute__((ext_vector_type(4))) __bf16 bf16x4;
typedef __attribute__((ext_vector_type(4))) float f32x4;

__device__ __forceinline__ float leaky(float x) {
    return x >= 0.0f ? x : NEG_SLOPE * x;
}

__device__ __forceinline__ float4 f4fma(float a, float4 b, float4 c) {
    c.x += a * b.x; c.y += a * b.y; c.z += a * b.z; c.w += a * b.w;
    return c;
}

__device__ __forceinline__ bf16x4 pack4(float4 v) {
    bf16x4 o;
    o[0] = (__bf16)v.x; o[1] = (__bf16)v.y; o[2] = (__bf16)v.z; o[3] = (__bf16)v.w;
    return o;
}

// ---------------- node encoder ----------------

__global__ void encode_nodes_kernel(const float* __restrict__ x,
                                    const float* __restrict__ W,  // [6][32]
                                    const float* __restrict__ b,  // [32]
                                    float* __restrict__ h,
                                    __bf16* __restrict__ hbf) {
    __shared__ __align__(16) float Ws[6 * 32];
    __shared__ __align__(16) float bs[32];
    int tid = threadIdx.x;
    if (tid < 192) Ws[tid] = W[tid];
    if (tid < 32) bs[tid] = b[tid];
    __syncthreads();
    int n = blockIdx.x * blockDim.x + tid;
    if (n >= N_NODES) return;
    float xv[6];
#pragma unroll
    for (int k = 0; k < 6; k++) xv[k] = x[(size_t)n * 6 + k];
    float4 acc[8];
#pragma unroll
    for (int q = 0; q < 8; q++) acc[q] = *(const float4*)&bs[q * 4];
#pragma unroll
    for (int k = 0; k < 6; k++) {
#pragma unroll
        for (int q = 0; q < 8; q++) {
            float4 w = *(const float4*)&Ws[k * 32 + q * 4];
            acc[q] = f4fma(xv[k], w, acc[q]);
        }
    }
#pragma unroll
    for (int q = 0; q < 8; q++) {
        float4 o = acc[q];
        o.x = leaky(o.x); o.y = leaky(o.y); o.z = leaky(o.z); o.w = leaky(o.w);
        *(float4*)&h[(size_t)n * 32 + q * 4] = o;
        *(bf16x4*)&hbf[(size_t)n * 32 + q * 4] = pack4(o);
    }
}

// ---------------- CSR build (once per launch) ----------------

__global__ void count_kernel(const int* __restrict__ recv, int* __restrict__ cnt) {
    int i = blockIdx.x * blockDim.x + threadIdx.x;
    if (i < N_EDGES) atomicAdd(&cnt[recv[i]], 1);
}

__global__ void csr_reduce_kernel(const int* __restrict__ cnt, int* __restrict__ partial) {
    __shared__ int sdata[SCAN_BLK];
    int tid = threadIdx.x;
    int idx = blockIdx.x * SCAN_BLK + tid;
    sdata[tid] = (idx < N_NODES) ? cnt[idx] : 0;
    __syncthreads();
#pragma unroll
    for (int off = SCAN_BLK / 2; off > 0; off >>= 1) {
        if (tid < off) sdata[tid] += sdata[tid + off];
        __syncthreads();
    }
    if (tid == 0) partial[blockIdx.x] = sdata[0];
}

__global__ void csr_scan_partials_kernel(int* __restrict__ partial,
                                         int* __restrict__ row_start) {
    __shared__ int sdata[SCAN_BLK];
    int tid = threadIdx.x;
    int v = (tid < SCAN_NBLK) ? partial[tid] : 0;
    sdata[tid] = v;
    __syncthreads();
#pragma unroll
    for (int off = 1; off < SCAN_BLK; off <<= 1) {
        int t = (tid >= off) ? sdata[tid - off] : 0;
        __syncthreads();
        sdata[tid] += t;
        __syncthreads();
    }
    if (tid < SCAN_NBLK) partial[tid] = sdata[tid] - v;  // exclusive
    if (tid == SCAN_BLK - 1) row_start[N_NODES] = sdata[SCAN_BLK - 1];
}

__global__ void csr_apply_kernel(const int* __restrict__ cnt,
                                 const int* __restrict__ partial,
                                 int* __restrict__ row_start,
                                 int* __restrict__ cursor) {
    __shared__ int sdata[SCAN_BLK];
    int tid = threadIdx.x;
    int idx = blockIdx.x * SCAN_BLK + tid;
    int v = (idx < N_NODES) ? cnt[idx] : 0;
    sdata[tid] = v;
    __syncthreads();
#pragma unroll
    for (int off = 1; off < SCAN_BLK; off <<= 1) {
        int t = (tid >= off) ? sdata[tid - off] : 0;
        __syncthreads();
        sdata[tid] += t;
        __syncthreads();
    }
    if (idx < N_NODES) {
        int out = partial[blockIdx.x] + sdata[tid] - v;
        row_start[idx] = out;
        cursor[idx] = out;
    }
}

// fused scatter + permute + edge-encode. Plain stores. (s,r) packed uint32.
// TOMBSTONE (round 14): nontemporal e-row stores = write-through/no-combine
// on gfx950 -> WRITE_SIZE 107->167 MB, dur 65->114 us. nt only for full-line
// single-instruction writes.
__global__ void scatter_encode_kernel(const float* __restrict__ ea,
                                      const int* __restrict__ senders,
                                      const int* __restrict__ receivers,
                                      int* __restrict__ cursor,
                                      const float* __restrict__ W,  // [3][32]
                                      const float* __restrict__ b,  // [32]
                                      __bf16* __restrict__ e,
                                      unsigned int* __restrict__ sr_p) {
    __shared__ __align__(16) float Ws[3 * 32];
    __shared__ __align__(16) float bs[32];
    int tid = threadIdx.x;
    if (tid < 96) Ws[tid] = W[tid];
    if (tid < 32) bs[tid] = b[tid];
    __syncthreads();
    int i = blockIdx.x * blockDim.x + tid;
    if (i >= N_EDGES) return;
    int s = senders[i];
    int r = receivers[i];
    float xv[3];
#pragma unroll
    for (int k = 0; k < 3; k++) xv[k] = ea[(size_t)i * 3 + k];
    int pos = atomicAdd(&cursor[r], 1);
    float4 acc[8];
#pragma unroll
    for (int q = 0; q < 8; q++) acc[q] = *(const float4*)&bs[q * 4];
#pragma unroll
    for (int k = 0; k < 3; k++) {
#pragma unroll
        for (int q = 0; q < 8; q++) {
            float4 w = *(const float4*)&Ws[k * 32 + q * 4];
            acc[q] = f4fma(xv[k], w, acc[q]);
        }
    }
    __bf16* er = e + (size_t)pos * 32;
#pragma unroll
    for (int q = 0; q < 4; q++) {
        float4 lo = acc[2 * q], hi = acc[2 * q + 1];
        bf16x8 v;
        v[0] = (__bf16)leaky(lo.x); v[1] = (__bf16)leaky(lo.y);
        v[2] = (__bf16)leaky(lo.z); v[3] = (__bf16)leaky(lo.w);
        v[4] = (__bf16)leaky(hi.x); v[5] = (__bf16)leaky(hi.y);
        v[6] = (__bf16)leaky(hi.z); v[7] = (__bf16)leaky(hi.w);
        *(bf16x8*)(er + q * 8) = v;
    }
    sr_p[pos] = (unsigned int)s | ((unsigned int)r << 16);
}

// ---------------- per-step edge update (MFMA, bf16 storage) ----------------
// ROUND-11 VERIFIED STRUCTURE: 1-deep software pipeline, runtime ntiles
// bound, NO unroll on the tile loop. TOMBSTONE: the 2-deep fully-unrolled
// variant (rounds 8-10) silently corrupts results — do NOT deepen without
// an LDS-fence redesign. TPW=4 (round 13). No W LDS staging (round 15:
// LDS 22->9.2 KB, 8 blocks/CU).

__global__ __launch_bounds__(256) void edge_mfma_kernel(
    __bf16* __restrict__ e,            // [E][32] in/out (receiver-sorted order)
    const __bf16* __restrict__ hbf,    // [N][32]
    const unsigned int* __restrict__ srp,  // [E] s | (r<<16)
    const float* __restrict__ W,       // [96][32]
    const float* __restrict__ bias,    // [32]
    const float* __restrict__ ln_s,    // [32]
    const float* __restrict__ ln_b) {  // [32]
    __shared__ __align__(16) float stg[4][16 * STG_STRIDE];
    int tid = threadIdx.x;

    const int wave = tid >> 6;
    const int lane = tid & 63;
    const int n_ = lane & 15;
    const int quad = lane >> 4;
    const int rr = lane >> 2;   // epilogue row 0..15
    const int jj = lane & 3;    // epilogue col-quarter

    // B fragments straight from global (L2-hot 12 KB, once per block)
    bf16x8 bf[3][2];
#pragma unroll
    for (int kc = 0; kc < 3; kc++)
#pragma unroll
        for (int oh = 0; oh < 2; oh++) {
            bf16x8 f;
#pragma unroll
            for (int j = 0; j < 8; j++)
                f[j] = (__bf16)W[(kc * 32 + quad * 8 + j) * 32 + oh * 16 + n_];
            bf[kc][oh] = f;
        }
    float bia0 = bias[n_], bia1 = bias[16 + n_];
    float lns8[8], lnb8[8];
    {
        f32x4 sa = *(const f32x4*)&ln_s[jj * 8];
        f32x4 sb = *(const f32x4*)&ln_s[jj * 8 + 4];
        f32x4 ba = *(const f32x4*)&ln_b[jj * 8];
        f32x4 bb = *(const f32x4*)&ln_b[jj * 8 + 4];
#pragma unroll
        for (int i = 0; i < 4; i++) {
            lns8[i] = sa[i]; lns8[4 + i] = sb[i];
            lnb8[i] = ba[i]; lnb8[4 + i] = bb[i];
        }
    }

    int tile0 = blockIdx.x * TILES_PER_BLOCK + wave * TPW;
    int ntiles = min(TPW, N_TILES - tile0);
    if (ntiles <= 0) return;
    float* mystg = stg[wave];
    const int ed0 = tile0 * 16 + n_;

    // pipeline prologue: tile 0's loads
    unsigned int sr0 = srp[ed0];
    bf16x8 aE = *(const bf16x8*)&e[(size_t)ed0 * 32 + quad * 8];
    bf16x8 aS = *(const bf16x8*)&hbf[(size_t)(sr0 & 0xFFFFu) * 32 + quad * 8];
    bf16x8 aR = *(const bf16x8*)&hbf[(size_t)(sr0 >> 16) * 32 + quad * 8];
    bf16x8 old = *(const bf16x8*)&e[(size_t)(tile0 * 16 + rr) * 32 + jj * 8];
    unsigned int sr_n = 0;
    if (ntiles > 1) sr_n = srp[ed0 + 16];

    for (int t = 0; t < ntiles; t++) {
        int e0 = (tile0 + t) * 16;

        f32x4 acc[2] = {{0.f, 0.f, 0.f, 0.f}, {0.f, 0.f, 0.f, 0.f}};
#pragma unroll
        for (int oh = 0; oh < 2; oh++) {
            acc[oh] = __builtin_amdgcn_mfma_f32_16x16x32_bf16(aE, bf[0][oh], acc[oh], 0, 0, 0);
            acc[oh] = __builtin_amdgcn_mfma_f32_16x16x32_bf16(aS, bf[1][oh], acc[oh], 0, 0, 0);
            acc[oh] = __builtin_amdgcn_mfma_f32_16x16x32_bf16(aR, bf[2][oh], acc[oh], 0, 0, 0);
        }

        // prefetch tile t+1 (loads overlap the epilogue below)
        bf16x8 aE_n = aE, aS_n = aS, aR_n = aR, old_n = old;
        if (t + 1 < ntiles) {
            int edn = ed0 + (t + 1) * 16;
            aE_n = *(const bf16x8*)&e[(size_t)edn * 32 + quad * 8];
            aS_n = *(const bf16x8*)&hbf[(size_t)(sr_n & 0xFFFFu) * 32 + quad * 8];
            aR_n = *(const bf16x8*)&hbf[(size_t)(sr_n >> 16) * 32 + quad * 8];
            old_n = *(const bf16x8*)&e[(size_t)(e0 + 16 + rr) * 32 + jj * 8];
            if (t + 2 < ntiles) sr_n = srp[ed0 + (t + 2) * 16];
        }

        // stage leaky(acc+bias) to LDS transpose buffer: [row quad*4+g][col oh*16+n_]
#pragma unroll
        for (int oh = 0; oh < 2; oh++)
#pragma unroll
            for (int g = 0; g < 4; g++)
                mystg[(quad * 4 + g) * STG_STRIDE + oh * 16 + n_] =
                    leaky(acc[oh][g] + (oh ? bia1 : bia0));
        __builtin_amdgcn_wave_barrier();

        // re-role: lane handles row rr, cols jj*8 .. jj*8+8
        f32x4 va = *(const f32x4*)&mystg[rr * STG_STRIDE + jj * 8];
        f32x4 vb = *(const f32x4*)&mystg[rr * STG_STRIDE + jj * 8 + 4];
        float s1 = va[0] + va[1] + va[2] + va[3] + vb[0] + vb[1] + vb[2] + vb[3];
        float s2 = va[0]*va[0] + va[1]*va[1] + va[2]*va[2] + va[3]*va[3]
                 + vb[0]*vb[0] + vb[1]*vb[1] + vb[2]*vb[2] + vb[3]*vb[3];
        s1 += __shfl_xor(s1, 1);  s2 += __shfl_xor(s2, 1);
        s1 += __shfl_xor(s1, 2);  s2 += __shfl_xor(s2, 2);
        float mu = s1 * (1.0f / 32.0f);
        float var = s2 * (1.0f / 32.0f) - mu * mu;
        float inv = rsqrtf(fmaxf(var, 0.0f) + LN_EPS);

        float v[8] = {va[0], va[1], va[2], va[3], vb[0], vb[1], vb[2], vb[3]};
        bf16x8 outp;
#pragma unroll
        for (int i = 0; i < 8; i++)
            outp[i] = (__bf16)((float)old[i] + (v[i] - mu) * inv * lns8[i] + lnb8[i]);
        *(bf16x8*)&e[(size_t)(e0 + rr) * 32 + jj * 8] = outp;  // coalesced 16B
        __builtin_amdgcn_wave_barrier();

        aE = aE_n; aS = aS_n; aR = aR_n; old = old_n;
    }
}

// ---------------- per-step fused aggregation + node update ----------------
// 1 thread per node. Grid = 781 waves over 256 CUs = ~3 waves/CU — the
// kernel is memory-parallelism-starved, not VALU-bound. SINGLE CHANGE THIS
// ROUND: 4x unroll of the degree loop — 16 independent 16B loads issued per
// iteration (~48 KB/CU in flight vs 12 KB before, BW-delay product ~22 KB).
// TOMBSTONE: 2-thread/node pair-split (round 12) regressed.

__global__ void node_kernel(float* __restrict__ h,
                            __bf16* __restrict__ hbf,
                            const __bf16* __restrict__ e,
                            const int* __restrict__ row_start,
                            const float* __restrict__ W,     // [64][32]
                            const float* __restrict__ bias,  // [32]
                            const float* __restrict__ ln_s,
                            const float* __restrict__ ln_b) {
    __shared__ __align__(16) float Ws[64 * 32];
    __shared__ __align__(16) float prm[96];
    int tid = threadIdx.x;
    {
        const float4* Wg = (const float4*)W;
        float4* Wl = (float4*)Ws;
#pragma unroll
        for (int r = 0; r < 2; r++) Wl[tid + r * 256] = Wg[tid + r * 256];
        if (tid < 32) {
            prm[tid] = bias[tid];
            prm[32 + tid] = ln_s[tid];
            prm[64 + tid] = ln_b[tid];
        }
    }
    __syncthreads();
    int n = blockIdx.x * blockDim.x + tid;
    if (n >= N_NODES) return;

    int beg = row_start[n], end = row_start[n + 1];
    float c[64];
#pragma unroll
    for (int q = 0; q < 8; q++) {
        float4 v = *(const float4*)&h[(size_t)n * 32 + q * 4];
        c[q * 4 + 0] = v.x; c[q * 4 + 1] = v.y; c[q * 4 + 2] = v.z; c[q * 4 + 3] = v.w;
    }
    float s[32];
#pragma unroll
    for (int k = 0; k < 32; k++) s[k] = 0.0f;

    int j = beg;
    for (; j + 3 < end; j += 4) {
        // issue all 16 loads before any accumulate (memory-level parallelism)
        bf16x8 v[16];
#pragma unroll
        for (int r = 0; r < 4; r++) {
            const __bf16* er = e + (size_t)(j + r) * 32;
#pragma unroll
            for (int q = 0; q < 4; q++) v[r * 4 + q] = *(const bf16x8*)(er + q * 8);
        }
#pragma unroll
        for (int r = 0; r < 4; r++)
#pragma unroll
            for (int q = 0; q < 4; q++)
#pragma unroll
                for (int k = 0; k < 8; k++)
                    s[q * 8 + k] += (float)v[r * 4 + q][k];
    }
    for (; j < end; j++) {
        const __bf16* er = e + (size_t)j * 32;
#pragma unroll
        for (int q = 0; q < 4; q++) {
            bf16x8 v = *(const bf16x8*)(er + q * 8);
#pragma unroll
            for (int k = 0; k < 8; k++) s[q * 8 + k] += (float)v[k];
        }
    }
    float ic = 1.0f / fmaxf((float)(end - beg), 1.0f);
#pragma unroll
    for (int k = 0; k < 32; k++) c[32 + k] = s[k] * ic;

    float4 acc[8];
#pragma unroll
    for (int q = 0; q < 8; q++) acc[q] = *(const float4*)&prm[q * 4];
#pragma unroll
    for (int k = 0; k < 64; k++) {
#pragma unroll
        for (int q = 0; q < 8; q++) {
            float4 w = *(const float4*)&Ws[k * 32 + q * 4];
            acc[q] = f4fma(c[k], w, acc[q]);
        }
    }
    float m[32];
#pragma unroll
    for (int q = 0; q < 8; q++) {
        m[q * 4 + 0] = leaky(acc[q].x);
        m[q * 4 + 1] = leaky(acc[q].y);
        m[q * 4 + 2] = leaky(acc[q].z);
        m[q * 4 + 3] = leaky(acc[q].w);
    }
    float s1 = 0.0f, s2 = 0.0f;
#pragma unroll
    for (int i = 0; i < 32; i++) { s1 += m[i]; s2 += m[i] * m[i]; }
    float mu = s1 * (1.0f / 32.0f);
    float var = s2 * (1.0f / 32.0f) - mu * mu;
    float inv = rsqrtf(fmaxf(var, 0.0f) + LN_EPS);
#pragma unroll
    for (int q = 0; q < 8; q++) {
        float4 sc = *(const float4*)&prm[32 + q * 4];
        float4 bi = *(const float4*)&prm[64 + q * 4];
        float4 res;
        res.x = c[q * 4 + 0] + (m[q * 4 + 0] - mu) * inv * sc.x + bi.x;
        res.y = c[q * 4 + 1] + (m[q * 4 + 1] - mu) * inv * sc.y + bi.y;
        res.z = c[q * 4 + 2] + (m[q * 4 + 2] - mu) * inv * sc.z + bi.z;
        res.w = c[q * 4 + 3] + (m[q * 4 + 3] - mu) * inv * sc.w + bi.w;
        *(float4*)&h[(size_t)n * 32 + q * 4] = res;
        *(bf16x4*)&hbf[(size_t)n * 32 + q * 4] = pack4(res);
    }
}

// ---------------- decoder ----------------

__global__ void decoder_kernel(const float* __restrict__ h,
                               const float* __restrict__ W1,  // [32][32]
                               const float* __restrict__ b1,  // [32]
                               const float* __restrict__ W2,  // [32][1]
                               const float* __restrict__ b2,  // [1]
                               float* __restrict__ out) {
    __shared__ __align__(16) float W1s[32 * 32];
    __shared__ __align__(16) float prm[65];
    int tid = threadIdx.x;
    {
        const float4* Wg = (const float4*)W1;
        float4* Wl = (float4*)W1s;
        Wl[tid] = Wg[tid];
        if (tid < 32) { prm[tid] = b1[tid]; prm[32 + tid] = W2[tid]; }
        if (tid == 0) prm[64] = b2[0];
    }
    __syncthreads();
    int n = blockIdx.x * blockDim.x + tid;
    if (n >= N_NODES) return;
    float hv[32];
#pragma unroll
    for (int q = 0; q < 8; q++) {
        float4 v = *(const float4*)&h[(size_t)n * 32 + q * 4];
        hv[q * 4 + 0] = v.x; hv[q * 4 + 1] = v.y; hv[q * 4 + 2] = v.z; hv[q * 4 + 3] = v.w;
    }
    float4 acc[8];
#pragma unroll
    for (int q = 0; q < 8; q++) acc[q] = *(const float4*)&prm[q * 4];
#pragma unroll
    for (int k = 0; k < 32; k++) {
#pragma unroll
        for (int q = 0; q < 8; q++) {
            float4 w = *(const float4*)&W1s[k * 32 + q * 4];
            acc[q] = f4fma(hv[k], w, acc[q]);
        }
    }
    float o = prm[64];
#pragma unroll
    for (int q = 0; q < 8; q++) {
        o += leaky(acc[q].x) * prm[32 + q * 4 + 0];
        o += leaky(acc[q].y) * prm[32 + q * 4 + 1];
        o += leaky(acc[q].z) * prm[32 + q * 4 + 2];
        o += leaky(acc[q].w) * prm[32 + q * 4 + 3];
    }
    out[n] = o;
}

// ---------------- launch ----------------

extern "C" void kernel_launch(void* const* d_in, const int* in_sizes, int n_in,
                              void* d_out, int out_size, void* d_ws, size_t ws_size,
                              hipStream_t stream) {
    const float* x          = (const float*)d_in[0];
    const float* edge_attr  = (const float*)d_in[1];
    const int*   senders    = (const int*)d_in[2];
    const int*   receivers  = (const int*)d_in[3];
    const float* node_enc_W = (const float*)d_in[4];
    const float* node_enc_b = (const float*)d_in[5];
    const float* edge_enc_W = (const float*)d_in[6];
    const float* edge_enc_b = (const float*)d_in[7];
    const float* edge_W     = (const float*)d_in[8];
    const float* edge_b     = (const float*)d_in[9];
    const float* edge_ln_s  = (const float*)d_in[10];
    const float* edge_ln_b  = (const float*)d_in[11];
    const float* node_W     = (const float*)d_in[12];
    const float* node_b     = (const float*)d_in[13];
    const float* node_ln_s  = (const float*)d_in[14];
    const float* node_ln_b  = (const float*)d_in[15];
    const float* dec_W1     = (const float*)d_in[16];
    const float* dec_b1     = (const float*)d_in[17];
    const float* dec_W2     = (const float*)d_in[18];
    const float* dec_b2     = (const float*)d_in[19];
    float* out = (float*)d_out;

    char* ws = (char*)d_ws;
    size_t off = 0;
    auto alloc = [&](size_t bytes) -> void* {
        void* p = ws + off;
        off = (off + bytes + 255) & ~(size_t)255;
        return p;
    };
    float*        h         = (float*)alloc((size_t)N_NODES * 32 * 4);
    __bf16*       hbf       = (__bf16*)alloc((size_t)N_NODES * 32 * 2);
    __bf16*       e         = (__bf16*)alloc((size_t)N_EDGES * 32 * 2);
    int*          cnt       = (int*)alloc((size_t)N_NODES * 4);
    int*          row_start = (int*)alloc((size_t)(N_NODES + 1) * 4);
    int*          cursor    = (int*)alloc((size_t)N_NODES * 4);
    unsigned int* sr_p      = (unsigned int*)alloc((size_t)N_EDGES * 4);
    int*          partial   = (int*)alloc((size_t)SCAN_BLK * 4);
    (void)ws_size; (void)in_sizes; (void)n_in; (void)out_size;

    hipMemsetAsync(cnt, 0, (size_t)N_NODES * 4, stream);
    encode_nodes_kernel<<<(N_NODES + 255) / 256, 256, 0, stream>>>(x, node_enc_W, node_enc_b, h, hbf);
    count_kernel<<<(N_EDGES + 255) / 256, 256, 0, stream>>>(receivers, cnt);
    csr_reduce_kernel<<<SCAN_NBLK, SCAN_BLK, 0, stream>>>(cnt, partial);
    csr_scan_partials_kernel<<<1, SCAN_BLK, 0, stream>>>(partial, row_start);
    csr_apply_kernel<<<SCAN_NBLK, SCAN_BLK, 0, stream>>>(cnt, partial, row_start, cursor);
    scatter_encode_kernel<<<(N_EDGES + 255) / 256, 256, 0, stream>>>(
        edge_attr, senders, receivers, cursor, edge_enc_W, edge_enc_b, e, sr_p);

    int edge_blocks = (N_TILES + TILES_PER_BLOCK - 1) / TILES_PER_BLOCK;
    for (int s = 0; s < STEPS; s++) {
        edge_mfma_kernel<<<edge_blocks, 256, 0, stream>>>(
            e, hbf, sr_p,
            edge_W + (size_t)s * 96 * 32, edge_b + s * 32,
            edge_ln_s + s * 32, edge_ln_b + s * 32);
        node_kernel<<<(N_NODES + 255) / 256, 256, 0, stream>>>(
            h, hbf, e, row_start, node_W + (size_t)s * 64 * 32, node_b + s * 32,
            node_ln_s + s * 32, node_ln_b + s * 32);
    }
    decoder_kernel<<<(N_NODES + 255) / 256, 256, 0, stream>>>(h, dec_W1, dec_b1, dec_W2, dec_b2, out);
}

// Round 17
// 719.224 us; speedup vs baseline: 1.5209x; 1.5209x over previous
//
#include <hip/hip_runtime.h>
#include <hip/hip_bf16.h>

#define N_NODES 50000
#define N_EDGES 800000
#define LATENT 32
#define STEPS 10
#define NEG_SLOPE 0.01f
#define LN_EPS 1e-5f
#define N_TILES (N_EDGES / 16)
#define TPW 4                 // tiles per wave (3125 blocks * 4 waves * 4 tiles = 50000)
#define TILES_PER_BLOCK 16    // 4 waves * TPW
#define SCAN_BLK 256
#define SCAN_NBLK ((N_NODES + SCAN_BLK - 1) / SCAN_BLK)  // 196
#define STG_STRIDE 36         // 16-row staging, +4 pad: 16B-aligned rows, 2-way banks

typedef __attribute__((ext_vector_type(8))) __bf16 bf16x8;
typedef __attribute__((ext_vector_type(4))) __bf16 bf16x4;
typedef __attribute__((ext_vector_type(4))) float f32x4;

__device__ __forceinline__ float leaky(float x) {
    return x >= 0.0f ? x : NEG_SLOPE * x;
}

__device__ __forceinline__ float4 f4fma(float a, float4 b, float4 c) {
    c.x += a * b.x; c.y += a * b.y; c.z += a * b.z; c.w += a * b.w;
    return c;
}

__device__ __forceinline__ bf16x4 pack4(float4 v) {
    bf16x4 o;
    o[0] = (__bf16)v.x; o[1] = (__bf16)v.y; o[2] = (__bf16)v.z; o[3] = (__bf16)v.w;
    return o;
}

// ---------------- node encoder ----------------

__global__ void encode_nodes_kernel(const float* __restrict__ x,
                                    const float* __restrict__ W,  // [6][32]
                                    const float* __restrict__ b,  // [32]
                                    float* __restrict__ h,
                                    __bf16* __restrict__ hbf) {
    __shared__ __align__(16) float Ws[6 * 32];
    __shared__ __align__(16) float bs[32];
    int tid = threadIdx.x;
    if (tid < 192) Ws[tid] = W[tid];
    if (tid < 32) bs[tid] = b[tid];
    __syncthreads();
    int n = blockIdx.x * blockDim.x + tid;
    if (n >= N_NODES) return;
    float xv[6];
#pragma unroll
    for (int k = 0; k < 6; k++) xv[k] = x[(size_t)n * 6 + k];
    float4 acc[8];
#pragma unroll
    for (int q = 0; q < 8; q++) acc[q] = *(const float4*)&bs[q * 4];
#pragma unroll
    for (int k = 0; k < 6; k++) {
#pragma unroll
        for (int q = 0; q < 8; q++) {
            float4 w = *(const float4*)&Ws[k * 32 + q * 4];
            acc[q] = f4fma(xv[k], w, acc[q]);
        }
    }
#pragma unroll
    for (int q = 0; q < 8; q++) {
        float4 o = acc[q];
        o.x = leaky(o.x); o.y = leaky(o.y); o.z = leaky(o.z); o.w = leaky(o.w);
        *(float4*)&h[(size_t)n * 32 + q * 4] = o;
        *(bf16x4*)&hbf[(size_t)n * 32 + q * 4] = pack4(o);
    }
}

// ---------------- CSR build (once per launch) ----------------

__global__ void count_kernel(const int* __restrict__ recv, int* __restrict__ cnt) {
    int i = blockIdx.x * blockDim.x + threadIdx.x;
    if (i < N_EDGES) atomicAdd(&cnt[recv[i]], 1);
}

__global__ void csr_reduce_kernel(const int* __restrict__ cnt, int* __restrict__ partial) {
    __shared__ int sdata[SCAN_BLK];
    int tid = threadIdx.x;
    int idx = blockIdx.x * SCAN_BLK + tid;
    sdata[tid] = (idx < N_NODES) ? cnt[idx] : 0;
    __syncthreads();
#pragma unroll
    for (int off = SCAN_BLK / 2; off > 0; off >>= 1) {
        if (tid < off) sdata[tid] += sdata[tid + off];
        __syncthreads();
    }
    if (tid == 0) partial[blockIdx.x] = sdata[0];
}

__global__ void csr_scan_partials_kernel(int* __restrict__ partial,
                                         int* __restrict__ row_start) {
    __shared__ int sdata[SCAN_BLK];
    int tid = threadIdx.x;
    int v = (tid < SCAN_NBLK) ? partial[tid] : 0;
    sdata[tid] = v;
    __syncthreads();
#pragma unroll
    for (int off = 1; off < SCAN_BLK; off <<= 1) {
        int t = (tid >= off) ? sdata[tid - off] : 0;
        __syncthreads();
        sdata[tid] += t;
        __syncthreads();
    }
    if (tid < SCAN_NBLK) partial[tid] = sdata[tid] - v;  // exclusive
    if (tid == SCAN_BLK - 1) row_start[N_NODES] = sdata[SCAN_BLK - 1];
}

__global__ void csr_apply_kernel(const int* __restrict__ cnt,
                                 const int* __restrict__ partial,
                                 int* __restrict__ row_start,
                                 int* __restrict__ cursor) {
    __shared__ int sdata[SCAN_BLK];
    int tid = threadIdx.x;
    int idx = blockIdx.x * SCAN_BLK + tid;
    int v = (idx < N_NODES) ? cnt[idx] : 0;
    sdata[tid] = v;
    __syncthreads();
#pragma unroll
    for (int off = 1; off < SCAN_BLK; off <<= 1) {
        int t = (tid >= off) ? sdata[tid - off] : 0;
        __syncthreads();
        sdata[tid] += t;
        __syncthreads();
    }
    if (idx < N_NODES) {
        int out = partial[blockIdx.x] + sdata[tid] - v;
        row_start[idx] = out;
        cursor[idx] = out;
    }
}

// fused scatter + permute + edge-encode. Plain stores. (s,r) packed uint32.
// TOMBSTONE (round 14): nontemporal e-row stores = write-through/no-combine
// on gfx950 -> WRITE_SIZE 107->167 MB, dur 65->114 us. nt only for full-line
// single-instruction writes.
__global__ void scatter_encode_kernel(const float* __restrict__ ea,
                                      const int* __restrict__ senders,
                                      const int* __restrict__ receivers,
                                      int* __restrict__ cursor,
                                      const float* __restrict__ W,  // [3][32]
                                      const float* __restrict__ b,  // [32]
                                      __bf16* __restrict__ e,
                                      unsigned int* __restrict__ sr_p) {
    __shared__ __align__(16) float Ws[3 * 32];
    __shared__ __align__(16) float bs[32];
    int tid = threadIdx.x;
    if (tid < 96) Ws[tid] = W[tid];
    if (tid < 32) bs[tid] = b[tid];
    __syncthreads();
    int i = blockIdx.x * blockDim.x + tid;
    if (i >= N_EDGES) return;
    int s = senders[i];
    int r = receivers[i];
    float xv[3];
#pragma unroll
    for (int k = 0; k < 3; k++) xv[k] = ea[(size_t)i * 3 + k];
    int pos = atomicAdd(&cursor[r], 1);
    float4 acc[8];
#pragma unroll
    for (int q = 0; q < 8; q++) acc[q] = *(const float4*)&bs[q * 4];
#pragma unroll
    for (int k = 0; k < 3; k++) {
#pragma unroll
        for (int q = 0; q < 8; q++) {
            float4 w = *(const float4*)&Ws[k * 32 + q * 4];
            acc[q] = f4fma(xv[k], w, acc[q]);
        }
    }
    __bf16* er = e + (size_t)pos * 32;
#pragma unroll
    for (int q = 0; q < 4; q++) {
        float4 lo = acc[2 * q], hi = acc[2 * q + 1];
        bf16x8 v;
        v[0] = (__bf16)leaky(lo.x); v[1] = (__bf16)leaky(lo.y);
        v[2] = (__bf16)leaky(lo.z); v[3] = (__bf16)leaky(lo.w);
        v[4] = (__bf16)leaky(hi.x); v[5] = (__bf16)leaky(hi.y);
        v[6] = (__bf16)leaky(hi.z); v[7] = (__bf16)leaky(hi.w);
        *(bf16x8*)(er + q * 8) = v;
    }
    sr_p[pos] = (unsigned int)s | ((unsigned int)r << 16);
}

// ---------------- per-step edge update (MFMA, bf16 storage) ----------------
// ROUND-11 VERIFIED STRUCTURE: 1-deep software pipeline, runtime ntiles
// bound, NO unroll on the tile loop. TOMBSTONE: the 2-deep fully-unrolled
// variant (rounds 8-10) silently corrupts results — do NOT deepen without
// an LDS-fence redesign. TPW=4 (round 13). No W LDS staging (round 15:
// LDS 22->9.2 KB, 8 blocks/CU).

__global__ __launch_bounds__(256) void edge_mfma_kernel(
    __bf16* __restrict__ e,            // [E][32] in/out (receiver-sorted order)
    const __bf16* __restrict__ hbf,    // [N][32]
    const unsigned int* __restrict__ srp,  // [E] s | (r<<16)
    const float* __restrict__ W,       // [96][32]
    const float* __restrict__ bias,    // [32]
    const float* __restrict__ ln_s,    // [32]
    const float* __restrict__ ln_b) {  // [32]
    __shared__ __align__(16) float stg[4][16 * STG_STRIDE];
    int tid = threadIdx.x;

    const int wave = tid >> 6;
    const int lane = tid & 63;
    const int n_ = lane & 15;
    const int quad = lane >> 4;
    const int rr = lane >> 2;   // epilogue row 0..15
    const int jj = lane & 3;    // epilogue col-quarter

    // B fragments straight from global (L2-hot 12 KB, once per block)
    bf16x8 bf[3][2];
#pragma unroll
    for (int kc = 0; kc < 3; kc++)
#pragma unroll
        for (int oh = 0; oh < 2; oh++) {
            bf16x8 f;
#pragma unroll
            for (int j = 0; j < 8; j++)
                f[j] = (__bf16)W[(kc * 32 + quad * 8 + j) * 32 + oh * 16 + n_];
            bf[kc][oh] = f;
        }
    float bia0 = bias[n_], bia1 = bias[16 + n_];
    float lns8[8], lnb8[8];
    {
        f32x4 sa = *(const f32x4*)&ln_s[jj * 8];
        f32x4 sb = *(const f32x4*)&ln_s[jj * 8 + 4];
        f32x4 ba = *(const f32x4*)&ln_b[jj * 8];
        f32x4 bb = *(const f32x4*)&ln_b[jj * 8 + 4];
#pragma unroll
        for (int i = 0; i < 4; i++) {
            lns8[i] = sa[i]; lns8[4 + i] = sb[i];
            lnb8[i] = ba[i]; lnb8[4 + i] = bb[i];
        }
    }

    int tile0 = blockIdx.x * TILES_PER_BLOCK + wave * TPW;
    int ntiles = min(TPW, N_TILES - tile0);
    if (ntiles <= 0) return;
    float* mystg = stg[wave];
    const int ed0 = tile0 * 16 + n_;

    // pipeline prologue: tile 0's loads
    unsigned int sr0 = srp[ed0];
    bf16x8 aE = *(const bf16x8*)&e[(size_t)ed0 * 32 + quad * 8];
    bf16x8 aS = *(const bf16x8*)&hbf[(size_t)(sr0 & 0xFFFFu) * 32 + quad * 8];
    bf16x8 aR = *(const bf16x8*)&hbf[(size_t)(sr0 >> 16) * 32 + quad * 8];
    bf16x8 old = *(const bf16x8*)&e[(size_t)(tile0 * 16 + rr) * 32 + jj * 8];
    unsigned int sr_n = 0;
    if (ntiles > 1) sr_n = srp[ed0 + 16];

    for (int t = 0; t < ntiles; t++) {
        int e0 = (tile0 + t) * 16;

        f32x4 acc[2] = {{0.f, 0.f, 0.f, 0.f}, {0.f, 0.f, 0.f, 0.f}};
#pragma unroll
        for (int oh = 0; oh < 2; oh++) {
            acc[oh] = __builtin_amdgcn_mfma_f32_16x16x32_bf16(aE, bf[0][oh], acc[oh], 0, 0, 0);
            acc[oh] = __builtin_amdgcn_mfma_f32_16x16x32_bf16(aS, bf[1][oh], acc[oh], 0, 0, 0);
            acc[oh] = __builtin_amdgcn_mfma_f32_16x16x32_bf16(aR, bf[2][oh], acc[oh], 0, 0, 0);
        }

        // prefetch tile t+1 (loads overlap the epilogue below)
        bf16x8 aE_n = aE, aS_n = aS, aR_n = aR, old_n = old;
        if (t + 1 < ntiles) {
            int edn = ed0 + (t + 1) * 16;
            aE_n = *(const bf16x8*)&e[(size_t)edn * 32 + quad * 8];
            aS_n = *(const bf16x8*)&hbf[(size_t)(sr_n & 0xFFFFu) * 32 + quad * 8];
            aR_n = *(const bf16x8*)&hbf[(size_t)(sr_n >> 16) * 32 + quad * 8];
            old_n = *(const bf16x8*)&e[(size_t)(e0 + 16 + rr) * 32 + jj * 8];
            if (t + 2 < ntiles) sr_n = srp[ed0 + (t + 2) * 16];
        }

        // stage leaky(acc+bias) to LDS transpose buffer: [row quad*4+g][col oh*16+n_]
#pragma unroll
        for (int oh = 0; oh < 2; oh++)
#pragma unroll
            for (int g = 0; g < 4; g++)
                mystg[(quad * 4 + g) * STG_STRIDE + oh * 16 + n_] =
                    leaky(acc[oh][g] + (oh ? bia1 : bia0));
        __builtin_amdgcn_wave_barrier();

        // re-role: lane handles row rr, cols jj*8 .. jj*8+8
        f32x4 va = *(const f32x4*)&mystg[rr * STG_STRIDE + jj * 8];
        f32x4 vb = *(const f32x4*)&mystg[rr * STG_STRIDE + jj * 8 + 4];
        float s1 = va[0] + va[1] + va[2] + va[3] + vb[0] + vb[1] + vb[2] + vb[3];
        float s2 = va[0]*va[0] + va[1]*va[1] + va[2]*va[2] + va[3]*va[3]
                 + vb[0]*vb[0] + vb[1]*vb[1] + vb[2]*vb[2] + vb[3]*vb[3];
        s1 += __shfl_xor(s1, 1);  s2 += __shfl_xor(s2, 1);
        s1 += __shfl_xor(s1, 2);  s2 += __shfl_xor(s2, 2);
        float mu = s1 * (1.0f / 32.0f);
        float var = s2 * (1.0f / 32.0f) - mu * mu;
        float inv = rsqrtf(fmaxf(var, 0.0f) + LN_EPS);

        float v[8] = {va[0], va[1], va[2], va[3], vb[0], vb[1], vb[2], vb[3]};
        bf16x8 outp;
#pragma unroll
        for (int i = 0; i < 8; i++)
            outp[i] = (__bf16)((float)old[i] + (v[i] - mu) * inv * lns8[i] + lnb8[i]);
        *(bf16x8*)&e[(size_t)(e0 + rr) * 32 + jj * 8] = outp;  // coalesced 16B
        __builtin_amdgcn_wave_barrier();

        aE = aE_n; aS = aS_n; aR = aR_n; old = old_n;
    }
}

// ---------------- per-step fused aggregation + node update ----------------
// 1 thread per node, plain degree loop (round-15 verified).
// TOMBSTONE (round 12): 2-thread/node pair-split regressed (BW-bound).
// TOMBSTONE (round 16): 4x unroll with v[16] buffer -> compiler capped
// VGPR at 64 and spilled c[64]/s[32] to scratch (FETCH+WRITE +65 MB,
// occupancy 6.5%, 722->1094 us). Check -Rpass-analysis before adding
// register-hungry buffers here.

__global__ void node_kernel(float* __restrict__ h,
                            __bf16* __restrict__ hbf,
                            const __bf16* __restrict__ e,
                            const int* __restrict__ row_start,
                            const float* __restrict__ W,     // [64][32]
                            const float* __restrict__ bias,  // [32]
                            const float* __restrict__ ln_s,
                            const float* __restrict__ ln_b) {
    __shared__ __align__(16) float Ws[64 * 32];
    __shared__ __align__(16) float prm[96];
    int tid = threadIdx.x;
    {
        const float4* Wg = (const float4*)W;
        float4* Wl = (float4*)Ws;
#pragma unroll
        for (int r = 0; r < 2; r++) Wl[tid + r * 256] = Wg[tid + r * 256];
        if (tid < 32) {
            prm[tid] = bias[tid];
            prm[32 + tid] = ln_s[tid];
            prm[64 + tid] = ln_b[tid];
        }
    }
    __syncthreads();
    int n = blockIdx.x * blockDim.x + tid;
    if (n >= N_NODES) return;

    int beg = row_start[n], end = row_start[n + 1];
    float c[64];
#pragma unroll
    for (int q = 0; q < 8; q++) {
        float4 v = *(const float4*)&h[(size_t)n * 32 + q * 4];
        c[q * 4 + 0] = v.x; c[q * 4 + 1] = v.y; c[q * 4 + 2] = v.z; c[q * 4 + 3] = v.w;
    }
    float s[32];
#pragma unroll
    for (int k = 0; k < 32; k++) s[k] = 0.0f;
    for (int j = beg; j < end; j++) {
        const __bf16* er = e + (size_t)j * 32;
#pragma unroll
        for (int q = 0; q < 4; q++) {
            bf16x8 v = *(const bf16x8*)(er + q * 8);
#pragma unroll
            for (int k = 0; k < 8; k++) s[q * 8 + k] += (float)v[k];
        }
    }
    float ic = 1.0f / fmaxf((float)(end - beg), 1.0f);
#pragma unroll
    for (int k = 0; k < 32; k++) c[32 + k] = s[k] * ic;

    float4 acc[8];
#pragma unroll
    for (int q = 0; q < 8; q++) acc[q] = *(const float4*)&prm[q * 4];
#pragma unroll
    for (int k = 0; k < 64; k++) {
#pragma unroll
        for (int q = 0; q < 8; q++) {
            float4 w = *(const float4*)&Ws[k * 32 + q * 4];
            acc[q] = f4fma(c[k], w, acc[q]);
        }
    }
    float m[32];
#pragma unroll
    for (int q = 0; q < 8; q++) {
        m[q * 4 + 0] = leaky(acc[q].x);
        m[q * 4 + 1] = leaky(acc[q].y);
        m[q * 4 + 2] = leaky(acc[q].z);
        m[q * 4 + 3] = leaky(acc[q].w);
    }
    float s1 = 0.0f, s2 = 0.0f;
#pragma unroll
    for (int i = 0; i < 32; i++) { s1 += m[i]; s2 += m[i] * m[i]; }
    float mu = s1 * (1.0f / 32.0f);
    float var = s2 * (1.0f / 32.0f) - mu * mu;
    float inv = rsqrtf(fmaxf(var, 0.0f) + LN_EPS);
#pragma unroll
    for (int q = 0; q < 8; q++) {
        float4 sc = *(const float4*)&prm[32 + q * 4];
        float4 bi = *(const float4*)&prm[64 + q * 4];
        float4 res;
        res.x = c[q * 4 + 0] + (m[q * 4 + 0] - mu) * inv * sc.x + bi.x;
        res.y = c[q * 4 + 1] + (m[q * 4 + 1] - mu) * inv * sc.y + bi.y;
        res.z = c[q * 4 + 2] + (m[q * 4 + 2] - mu) * inv * sc.z + bi.z;
        res.w = c[q * 4 + 3] + (m[q * 4 + 3] - mu) * inv * sc.w + bi.w;
        *(float4*)&h[(size_t)n * 32 + q * 4] = res;
        *(bf16x4*)&hbf[(size_t)n * 32 + q * 4] = pack4(res);
    }
}

// ---------------- decoder ----------------

__global__ void decoder_kernel(const float* __restrict__ h,
                               const float* __restrict__ W1,  // [32][32]
                               const float* __restrict__ b1,  // [32]
                               const float* __restrict__ W2,  // [32][1]
                               const float* __restrict__ b2,  // [1]
                               float* __restrict__ out) {
    __shared__ __align__(16) float W1s[32 * 32];
    __shared__ __align__(16) float prm[65];
    int tid = threadIdx.x;
    {
        const float4* Wg = (const float4*)W1;
        float4* Wl = (float4*)W1s;
        Wl[tid] = Wg[tid];
        if (tid < 32) { prm[tid] = b1[tid]; prm[32 + tid] = W2[tid]; }
        if (tid == 0) prm[64] = b2[0];
    }
    __syncthreads();
    int n = blockIdx.x * blockDim.x + tid;
    if (n >= N_NODES) return;
    float hv[32];
#pragma unroll
    for (int q = 0; q < 8; q++) {
        float4 v = *(const float4*)&h[(size_t)n * 32 + q * 4];
        hv[q * 4 + 0] = v.x; hv[q * 4 + 1] = v.y; hv[q * 4 + 2] = v.z; hv[q * 4 + 3] = v.w;
    }
    float4 acc[8];
#pragma unroll
    for (int q = 0; q < 8; q++) acc[q] = *(const float4*)&prm[q * 4];
#pragma unroll
    for (int k = 0; k < 32; k++) {
#pragma unroll
        for (int q = 0; q < 8; q++) {
            float4 w = *(const float4*)&W1s[k * 32 + q * 4];
            acc[q] = f4fma(hv[k], w, acc[q]);
        }
    }
    float o = prm[64];
#pragma unroll
    for (int q = 0; q < 8; q++) {
        o += leaky(acc[q].x) * prm[32 + q * 4 + 0];
        o += leaky(acc[q].y) * prm[32 + q * 4 + 1];
        o += leaky(acc[q].z) * prm[32 + q * 4 + 2];
        o += leaky(acc[q].w) * prm[32 + q * 4 + 3];
    }
    out[n] = o;
}

// ---------------- launch ----------------

extern "C" void kernel_launch(void* const* d_in, const int* in_sizes, int n_in,
                              void* d_out, int out_size, void* d_ws, size_t ws_size,
                              hipStream_t stream) {
    const float* x          = (const float*)d_in[0];
    const float* edge_attr  = (const float*)d_in[1];
    const int*   senders    = (const int*)d_in[2];
    const int*   receivers  = (const int*)d_in[3];
    const float* node_enc_W = (const float*)d_in[4];
    const float* node_enc_b = (const float*)d_in[5];
    const float* edge_enc_W = (const float*)d_in[6];
    const float* edge_enc_b = (const float*)d_in[7];
    const float* edge_W     = (const float*)d_in[8];
    const float* edge_b     = (const float*)d_in[9];
    const float* edge_ln_s  = (const float*)d_in[10];
    const float* edge_ln_b  = (const float*)d_in[11];
    const float* node_W     = (const float*)d_in[12];
    const float* node_b     = (const float*)d_in[13];
    const float* node_ln_s  = (const float*)d_in[14];
    const float* node_ln_b  = (const float*)d_in[15];
    const float* dec_W1     = (const float*)d_in[16];
    const float* dec_b1     = (const float*)d_in[17];
    const float* dec_W2     = (const float*)d_in[18];
    const float* dec_b2     = (const float*)d_in[19];
    float* out = (float*)d_out;

    char* ws = (char*)d_ws;
    size_t off = 0;
    auto alloc = [&](size_t bytes) -> void* {
        void* p = ws + off;
        off = (off + bytes + 255) & ~(size_t)255;
        return p;
    };
    float*        h         = (float*)alloc((size_t)N_NODES * 32 * 4);
    __bf16*       hbf       = (__bf16*)alloc((size_t)N_NODES * 32 * 2);
    __bf16*       e         = (__bf16*)alloc((size_t)N_EDGES * 32 * 2);
    int*          cnt       = (int*)alloc((size_t)N_NODES * 4);
    int*          row_start = (int*)alloc((size_t)(N_NODES + 1) * 4);
    int*          cursor    = (int*)alloc((size_t)N_NODES * 4);
    unsigned int* sr_p      = (unsigned int*)alloc((size_t)N_EDGES * 4);
    int*          partial   = (int*)alloc((size_t)SCAN_BLK * 4);
    (void)ws_size; (void)in_sizes; (void)n_in; (void)out_size;

    hipMemsetAsync(cnt, 0, (size_t)N_NODES * 4, stream);
    encode_nodes_kernel<<<(N_NODES + 255) / 256, 256, 0, stream>>>(x, node_enc_W, node_enc_b, h, hbf);
    count_kernel<<<(N_EDGES + 255) / 256, 256, 0, stream>>>(receivers, cnt);
    csr_reduce_kernel<<<SCAN_NBLK, SCAN_BLK, 0, stream>>>(cnt, partial);
    csr_scan_partials_kernel<<<1, SCAN_BLK, 0, stream>>>(partial, row_start);
    csr_apply_kernel<<<SCAN_NBLK, SCAN_BLK, 0, stream>>>(cnt, partial, row_start, cursor);
    scatter_encode_kernel<<<(N_EDGES + 255) / 256, 256, 0, stream>>>(
        edge_attr, senders, receivers, cursor, edge_enc_W, edge_enc_b, e, sr_p);

    int edge_blocks = (N_TILES + TILES_PER_BLOCK - 1) / TILES_PER_BLOCK;
    for (int s = 0; s < STEPS; s++) {
        edge_mfma_kernel<<<edge_blocks, 256, 0, stream>>>(
            e, hbf, sr_p,
            edge_W + (size_t)s * 96 * 32, edge_b + s * 32,
            edge_ln_s + s * 32, edge_ln_b + s * 32);
        node_kernel<<<(N_NODES + 255) / 256, 256, 0, stream>>>(
            h, hbf, e, row_start, node_W + (size_t)s * 64 * 32, node_b + s * 32,
            node_ln_s + s * 32, node_ln_b + s * 32);
    }
    decoder_kernel<<<(N_NODES + 255) / 256, 256, 0, stream>>>(h, dec_W1, dec_b1, dec_W2, dec_b2, out);
}

// Round 18
// 677.510 us; speedup vs baseline: 1.6145x; 1.0616x over previous
//
#include <hip/hip_runtime.h>
#include <hip/hip_bf16.h>

#define N_NODES 50000
#define N_EDGES 800000
#define LATENT 32
#define STEPS 10
#define NEG_SLOPE 0.01f
#define LN_EPS 1e-5f
#define N_TILES (N_EDGES / 16)
#define TPW 4                 // tiles per wave (3125 blocks * 4 waves * 4 tiles = 50000)
#define TILES_PER_BLOCK 16    // 4 waves * TPW
#define SCAN_BLK 256
#define SCAN_NBLK ((N_NODES + SCAN_BLK - 1) / SCAN_BLK)  // 196
#define STG_STRIDE 36         // 16-row staging, +4 pad: 16B-aligned rows, 2-way banks

typedef __attribute__((ext_vector_type(8))) __bf16 bf16x8;
typedef __attribute__((ext_vector_type(4))) __bf16 bf16x4;
typedef __attribute__((ext_vector_type(4))) float f32x4;

__device__ __forceinline__ float leaky(float x) {
    return x >= 0.0f ? x : NEG_SLOPE * x;
}

__device__ __forceinline__ float4 f4fma(float a, float4 b, float4 c) {
    c.x += a * b.x; c.y += a * b.y; c.z += a * b.z; c.w += a * b.w;
    return c;
}

__device__ __forceinline__ bf16x4 pack4(float4 v) {
    bf16x4 o;
    o[0] = (__bf16)v.x; o[1] = (__bf16)v.y; o[2] = (__bf16)v.z; o[3] = (__bf16)v.w;
    return o;
}

// ---------------- node encoder ----------------

__global__ void encode_nodes_kernel(const float* __restrict__ x,
                                    const float* __restrict__ W,  // [6][32]
                                    const float* __restrict__ b,  // [32]
                                    float* __restrict__ h,
                                    __bf16* __restrict__ hbf) {
    __shared__ __align__(16) float Ws[6 * 32];
    __shared__ __align__(16) float bs[32];
    int tid = threadIdx.x;
    if (tid < 192) Ws[tid] = W[tid];
    if (tid < 32) bs[tid] = b[tid];
    __syncthreads();
    int n = blockIdx.x * blockDim.x + tid;
    if (n >= N_NODES) return;
    float xv[6];
#pragma unroll
    for (int k = 0; k < 6; k++) xv[k] = x[(size_t)n * 6 + k];
    float4 acc[8];
#pragma unroll
    for (int q = 0; q < 8; q++) acc[q] = *(const float4*)&bs[q * 4];
#pragma unroll
    for (int k = 0; k < 6; k++) {
#pragma unroll
        for (int q = 0; q < 8; q++) {
            float4 w = *(const float4*)&Ws[k * 32 + q * 4];
            acc[q] = f4fma(xv[k], w, acc[q]);
        }
    }
#pragma unroll
    for (int q = 0; q < 8; q++) {
        float4 o = acc[q];
        o.x = leaky(o.x); o.y = leaky(o.y); o.z = leaky(o.z); o.w = leaky(o.w);
        *(float4*)&h[(size_t)n * 32 + q * 4] = o;
        *(bf16x4*)&hbf[(size_t)n * 32 + q * 4] = pack4(o);
    }
}

// ---------------- CSR build (once per launch) ----------------

__global__ void count_kernel(const int* __restrict__ recv, int* __restrict__ cnt) {
    int i = blockIdx.x * blockDim.x + threadIdx.x;
    if (i < N_EDGES) atomicAdd(&cnt[recv[i]], 1);
}

__global__ void csr_reduce_kernel(const int* __restrict__ cnt, int* __restrict__ partial) {
    __shared__ int sdata[SCAN_BLK];
    int tid = threadIdx.x;
    int idx = blockIdx.x * SCAN_BLK + tid;
    sdata[tid] = (idx < N_NODES) ? cnt[idx] : 0;
    __syncthreads();
#pragma unroll
    for (int off = SCAN_BLK / 2; off > 0; off >>= 1) {
        if (tid < off) sdata[tid] += sdata[tid + off];
        __syncthreads();
    }
    if (tid == 0) partial[blockIdx.x] = sdata[0];
}

__global__ void csr_scan_partials_kernel(int* __restrict__ partial,
                                         int* __restrict__ row_start) {
    __shared__ int sdata[SCAN_BLK];
    int tid = threadIdx.x;
    int v = (tid < SCAN_NBLK) ? partial[tid] : 0;
    sdata[tid] = v;
    __syncthreads();
#pragma unroll
    for (int off = 1; off < SCAN_BLK; off <<= 1) {
        int t = (tid >= off) ? sdata[tid - off] : 0;
        __syncthreads();
        sdata[tid] += t;
        __syncthreads();
    }
    if (tid < SCAN_NBLK) partial[tid] = sdata[tid] - v;  // exclusive
    if (tid == SCAN_BLK - 1) row_start[N_NODES] = sdata[SCAN_BLK - 1];
}

__global__ void csr_apply_kernel(const int* __restrict__ cnt,
                                 const int* __restrict__ partial,
                                 int* __restrict__ row_start,
                                 int* __restrict__ cursor) {
    __shared__ int sdata[SCAN_BLK];
    int tid = threadIdx.x;
    int idx = blockIdx.x * SCAN_BLK + tid;
    int v = (idx < N_NODES) ? cnt[idx] : 0;
    sdata[tid] = v;
    __syncthreads();
#pragma unroll
    for (int off = 1; off < SCAN_BLK; off <<= 1) {
        int t = (tid >= off) ? sdata[tid - off] : 0;
        __syncthreads();
        sdata[tid] += t;
        __syncthreads();
    }
    if (idx < N_NODES) {
        int out = partial[blockIdx.x] + sdata[tid] - v;
        row_start[idx] = out;
        cursor[idx] = out;
    }
}

// fused scatter + permute + edge-encode. Plain stores. (s,r) packed uint32.
// TOMBSTONE (round 14): nontemporal e-row stores = write-through/no-combine
// on gfx950 -> WRITE_SIZE 107->167 MB, dur 65->114 us. nt only for full-line
// single-instruction writes.
__global__ void scatter_encode_kernel(const float* __restrict__ ea,
                                      const int* __restrict__ senders,
                                      const int* __restrict__ receivers,
                                      int* __restrict__ cursor,
                                      const float* __restrict__ W,  // [3][32]
                                      const float* __restrict__ b,  // [32]
                                      __bf16* __restrict__ e,
                                      unsigned int* __restrict__ sr_p) {
    __shared__ __align__(16) float Ws[3 * 32];
    __shared__ __align__(16) float bs[32];
    int tid = threadIdx.x;
    if (tid < 96) Ws[tid] = W[tid];
    if (tid < 32) bs[tid] = b[tid];
    __syncthreads();
    int i = blockIdx.x * blockDim.x + tid;
    if (i >= N_EDGES) return;
    int s = senders[i];
    int r = receivers[i];
    float xv[3];
#pragma unroll
    for (int k = 0; k < 3; k++) xv[k] = ea[(size_t)i * 3 + k];
    int pos = atomicAdd(&cursor[r], 1);
    float4 acc[8];
#pragma unroll
    for (int q = 0; q < 8; q++) acc[q] = *(const float4*)&bs[q * 4];
#pragma unroll
    for (int k = 0; k < 3; k++) {
#pragma unroll
        for (int q = 0; q < 8; q++) {
            float4 w = *(const float4*)&Ws[k * 32 + q * 4];
            acc[q] = f4fma(xv[k], w, acc[q]);
        }
    }
    __bf16* er = e + (size_t)pos * 32;
#pragma unroll
    for (int q = 0; q < 4; q++) {
        float4 lo = acc[2 * q], hi = acc[2 * q + 1];
        bf16x8 v;
        v[0] = (__bf16)leaky(lo.x); v[1] = (__bf16)leaky(lo.y);
        v[2] = (__bf16)leaky(lo.z); v[3] = (__bf16)leaky(lo.w);
        v[4] = (__bf16)leaky(hi.x); v[5] = (__bf16)leaky(hi.y);
        v[6] = (__bf16)leaky(hi.z); v[7] = (__bf16)leaky(hi.w);
        *(bf16x8*)(er + q * 8) = v;
    }
    sr_p[pos] = (unsigned int)s | ((unsigned int)r << 16);
}

// ---------------- per-step edge update (MFMA, bf16 storage) ----------------
// ROUND-11 VERIFIED STRUCTURE: 1-deep software pipeline, runtime ntiles
// bound, NO unroll on the tile loop. TOMBSTONE: the 2-deep fully-unrolled
// variant (rounds 8-10) silently corrupts results — do NOT deepen without
// an LDS-fence redesign. TPW=4 (round 13). No W LDS staging (round 15:
// LDS 22->9.2 KB, 8 blocks/CU).

__global__ __launch_bounds__(256) void edge_mfma_kernel(
    __bf16* __restrict__ e,            // [E][32] in/out (receiver-sorted order)
    const __bf16* __restrict__ hbf,    // [N][32]
    const unsigned int* __restrict__ srp,  // [E] s | (r<<16)
    const float* __restrict__ W,       // [96][32]
    const float* __restrict__ bias,    // [32]
    const float* __restrict__ ln_s,    // [32]
    const float* __restrict__ ln_b) {  // [32]
    __shared__ __align__(16) float stg[4][16 * STG_STRIDE];
    int tid = threadIdx.x;

    const int wave = tid >> 6;
    const int lane = tid & 63;
    const int n_ = lane & 15;
    const int quad = lane >> 4;
    const int rr = lane >> 2;   // epilogue row 0..15
    const int jj = lane & 3;    // epilogue col-quarter

    // B fragments straight from global (L2-hot 12 KB, once per block)
    bf16x8 bf[3][2];
#pragma unroll
    for (int kc = 0; kc < 3; kc++)
#pragma unroll
        for (int oh = 0; oh < 2; oh++) {
            bf16x8 f;
#pragma unroll
            for (int j = 0; j < 8; j++)
                f[j] = (__bf16)W[(kc * 32 + quad * 8 + j) * 32 + oh * 16 + n_];
            bf[kc][oh] = f;
        }
    float bia0 = bias[n_], bia1 = bias[16 + n_];
    float lns8[8], lnb8[8];
    {
        f32x4 sa = *(const f32x4*)&ln_s[jj * 8];
        f32x4 sb = *(const f32x4*)&ln_s[jj * 8 + 4];
        f32x4 ba = *(const f32x4*)&ln_b[jj * 8];
        f32x4 bb = *(const f32x4*)&ln_b[jj * 8 + 4];
#pragma unroll
        for (int i = 0; i < 4; i++) {
            lns8[i] = sa[i]; lns8[4 + i] = sb[i];
            lnb8[i] = ba[i]; lnb8[4 + i] = bb[i];
        }
    }

    int tile0 = blockIdx.x * TILES_PER_BLOCK + wave * TPW;
    int ntiles = min(TPW, N_TILES - tile0);
    if (ntiles <= 0) return;
    float* mystg = stg[wave];
    const int ed0 = tile0 * 16 + n_;

    // pipeline prologue: tile 0's loads
    unsigned int sr0 = srp[ed0];
    bf16x8 aE = *(const bf16x8*)&e[(size_t)ed0 * 32 + quad * 8];
    bf16x8 aS = *(const bf16x8*)&hbf[(size_t)(sr0 & 0xFFFFu) * 32 + quad * 8];
    bf16x8 aR = *(const bf16x8*)&hbf[(size_t)(sr0 >> 16) * 32 + quad * 8];
    bf16x8 old = *(const bf16x8*)&e[(size_t)(tile0 * 16 + rr) * 32 + jj * 8];
    unsigned int sr_n = 0;
    if (ntiles > 1) sr_n = srp[ed0 + 16];

    for (int t = 0; t < ntiles; t++) {
        int e0 = (tile0 + t) * 16;

        f32x4 acc[2] = {{0.f, 0.f, 0.f, 0.f}, {0.f, 0.f, 0.f, 0.f}};
#pragma unroll
        for (int oh = 0; oh < 2; oh++) {
            acc[oh] = __builtin_amdgcn_mfma_f32_16x16x32_bf16(aE, bf[0][oh], acc[oh], 0, 0, 0);
            acc[oh] = __builtin_amdgcn_mfma_f32_16x16x32_bf16(aS, bf[1][oh], acc[oh], 0, 0, 0);
            acc[oh] = __builtin_amdgcn_mfma_f32_16x16x32_bf16(aR, bf[2][oh], acc[oh], 0, 0, 0);
        }

        // prefetch tile t+1 (loads overlap the epilogue below)
        bf16x8 aE_n = aE, aS_n = aS, aR_n = aR, old_n = old;
        if (t + 1 < ntiles) {
            int edn = ed0 + (t + 1) * 16;
            aE_n = *(const bf16x8*)&e[(size_t)edn * 32 + quad * 8];
            aS_n = *(const bf16x8*)&hbf[(size_t)(sr_n & 0xFFFFu) * 32 + quad * 8];
            aR_n = *(const bf16x8*)&hbf[(size_t)(sr_n >> 16) * 32 + quad * 8];
            old_n = *(const bf16x8*)&e[(size_t)(e0 + 16 + rr) * 32 + jj * 8];
            if (t + 2 < ntiles) sr_n = srp[ed0 + (t + 2) * 16];
        }

        // stage leaky(acc+bias) to LDS transpose buffer: [row quad*4+g][col oh*16+n_]
#pragma unroll
        for (int oh = 0; oh < 2; oh++)
#pragma unroll
            for (int g = 0; g < 4; g++)
                mystg[(quad * 4 + g) * STG_STRIDE + oh * 16 + n_] =
                    leaky(acc[oh][g] + (oh ? bia1 : bia0));
        __builtin_amdgcn_wave_barrier();

        // re-role: lane handles row rr, cols jj*8 .. jj*8+8
        f32x4 va = *(const f32x4*)&mystg[rr * STG_STRIDE + jj * 8];
        f32x4 vb = *(const f32x4*)&mystg[rr * STG_STRIDE + jj * 8 + 4];
        float s1 = va[0] + va[1] + va[2] + va[3] + vb[0] + vb[1] + vb[2] + vb[3];
        float s2 = va[0]*va[0] + va[1]*va[1] + va[2]*va[2] + va[3]*va[3]
                 + vb[0]*vb[0] + vb[1]*vb[1] + vb[2]*vb[2] + vb[3]*vb[3];
        s1 += __shfl_xor(s1, 1);  s2 += __shfl_xor(s2, 1);
        s1 += __shfl_xor(s1, 2);  s2 += __shfl_xor(s2, 2);
        float mu = s1 * (1.0f / 32.0f);
        float var = s2 * (1.0f / 32.0f) - mu * mu;
        float inv = rsqrtf(fmaxf(var, 0.0f) + LN_EPS);

        float v[8] = {va[0], va[1], va[2], va[3], vb[0], vb[1], vb[2], vb[3]};
        bf16x8 outp;
#pragma unroll
        for (int i = 0; i < 8; i++)
            outp[i] = (__bf16)((float)old[i] + (v[i] - mu) * inv * lns8[i] + lnb8[i]);
        *(bf16x8*)&e[(size_t)(e0 + rr) * 32 + jj * 8] = outp;  // coalesced 16B
        __builtin_amdgcn_wave_barrier();

        aE = aE_n; aS = aS_n; aR = aR_n; old = old_n;
    }
}

// ---------------- per-step fused aggregation + node update ----------------
// 1 thread per node; grid-limited to ~3 waves/CU, so VGPRs are free up to
// the spill point. __launch_bounds__(256, 1) lifts the compiler's default
// 64-VGPR occupancy cap — that cap is what made round 16's 4x unroll spill
// (VGPR_Count=64, +65 MB scratch traffic, 722->1094 us). With the cap
// lifted, the same unroll keeps 16 independent 16B loads in flight
// (~48 KB/CU > ~22 KB BW-delay product) with zero spill.
// TOMBSTONE (round 12): 2-thread/node pair-split regressed (BW-bound).

__global__ __launch_bounds__(256, 1) void node_kernel(
                            float* __restrict__ h,
                            __bf16* __restrict__ hbf,
                            const __bf16* __restrict__ e,
                            const int* __restrict__ row_start,
                            const float* __restrict__ W,     // [64][32]
                            const float* __restrict__ bias,  // [32]
                            const float* __restrict__ ln_s,
                            const float* __restrict__ ln_b) {
    __shared__ __align__(16) float Ws[64 * 32];
    __shared__ __align__(16) float prm[96];
    int tid = threadIdx.x;
    {
        const float4* Wg = (const float4*)W;
        float4* Wl = (float4*)Ws;
#pragma unroll
        for (int r = 0; r < 2; r++) Wl[tid + r * 256] = Wg[tid + r * 256];
        if (tid < 32) {
            prm[tid] = bias[tid];
            prm[32 + tid] = ln_s[tid];
            prm[64 + tid] = ln_b[tid];
        }
    }
    __syncthreads();
    int n = blockIdx.x * blockDim.x + tid;
    if (n >= N_NODES) return;

    int beg = row_start[n], end = row_start[n + 1];
    float c[64];
#pragma unroll
    for (int q = 0; q < 8; q++) {
        float4 v = *(const float4*)&h[(size_t)n * 32 + q * 4];
        c[q * 4 + 0] = v.x; c[q * 4 + 1] = v.y; c[q * 4 + 2] = v.z; c[q * 4 + 3] = v.w;
    }
    float s[32];
#pragma unroll
    for (int k = 0; k < 32; k++) s[k] = 0.0f;

    int j = beg;
    for (; j + 3 < end; j += 4) {
        // issue all 16 loads before any accumulate (memory-level parallelism)
        bf16x8 v[16];
#pragma unroll
        for (int r = 0; r < 4; r++) {
            const __bf16* er = e + (size_t)(j + r) * 32;
#pragma unroll
            for (int q = 0; q < 4; q++) v[r * 4 + q] = *(const bf16x8*)(er + q * 8);
        }
#pragma unroll
        for (int r = 0; r < 4; r++)
#pragma unroll
            for (int q = 0; q < 4; q++)
#pragma unroll
                for (int k = 0; k < 8; k++)
                    s[q * 8 + k] += (float)v[r * 4 + q][k];
    }
    for (; j < end; j++) {
        const __bf16* er = e + (size_t)j * 32;
#pragma unroll
        for (int q = 0; q < 4; q++) {
            bf16x8 v = *(const bf16x8*)(er + q * 8);
#pragma unroll
            for (int k = 0; k < 8; k++) s[q * 8 + k] += (float)v[k];
        }
    }
    float ic = 1.0f / fmaxf((float)(end - beg), 1.0f);
#pragma unroll
    for (int k = 0; k < 32; k++) c[32 + k] = s[k] * ic;

    float4 acc[8];
#pragma unroll
    for (int q = 0; q < 8; q++) acc[q] = *(const float4*)&prm[q * 4];
#pragma unroll
    for (int k = 0; k < 64; k++) {
#pragma unroll
        for (int q = 0; q < 8; q++) {
            float4 w = *(const float4*)&Ws[k * 32 + q * 4];
            acc[q] = f4fma(c[k], w, acc[q]);
        }
    }
    float m[32];
#pragma unroll
    for (int q = 0; q < 8; q++) {
        m[q * 4 + 0] = leaky(acc[q].x);
        m[q * 4 + 1] = leaky(acc[q].y);
        m[q * 4 + 2] = leaky(acc[q].z);
        m[q * 4 + 3] = leaky(acc[q].w);
    }
    float s1 = 0.0f, s2 = 0.0f;
#pragma unroll
    for (int i = 0; i < 32; i++) { s1 += m[i]; s2 += m[i] * m[i]; }
    float mu = s1 * (1.0f / 32.0f);
    float var = s2 * (1.0f / 32.0f) - mu * mu;
    float inv = rsqrtf(fmaxf(var, 0.0f) + LN_EPS);
#pragma unroll
    for (int q = 0; q < 8; q++) {
        float4 sc = *(const float4*)&prm[32 + q * 4];
        float4 bi = *(const float4*)&prm[64 + q * 4];
        float4 res;
        res.x = c[q * 4 + 0] + (m[q * 4 + 0] - mu) * inv * sc.x + bi.x;
        res.y = c[q * 4 + 1] + (m[q * 4 + 1] - mu) * inv * sc.y + bi.y;
        res.z = c[q * 4 + 2] + (m[q * 4 + 2] - mu) * inv * sc.z + bi.z;
        res.w = c[q * 4 + 3] + (m[q * 4 + 3] - mu) * inv * sc.w + bi.w;
        *(float4*)&h[(size_t)n * 32 + q * 4] = res;
        *(bf16x4*)&hbf[(size_t)n * 32 + q * 4] = pack4(res);
    }
}

// ---------------- decoder ----------------

__global__ void decoder_kernel(const float* __restrict__ h,
                               const float* __restrict__ W1,  // [32][32]
                               const float* __restrict__ b1,  // [32]
                               const float* __restrict__ W2,  // [32][1]
                               const float* __restrict__ b2,  // [1]
                               float* __restrict__ out) {
    __shared__ __align__(16) float W1s[32 * 32];
    __shared__ __align__(16) float prm[65];
    int tid = threadIdx.x;
    {
        const float4* Wg = (const float4*)W1;
        float4* Wl = (float4*)W1s;
        Wl[tid] = Wg[tid];
        if (tid < 32) { prm[tid] = b1[tid]; prm[32 + tid] = W2[tid]; }
        if (tid == 0) prm[64] = b2[0];
    }
    __syncthreads();
    int n = blockIdx.x * blockDim.x + tid;
    if (n >= N_NODES) return;
    float hv[32];
#pragma unroll
    for (int q = 0; q < 8; q++) {
        float4 v = *(const float4*)&h[(size_t)n * 32 + q * 4];
        hv[q * 4 + 0] = v.x; hv[q * 4 + 1] = v.y; hv[q * 4 + 2] = v.z; hv[q * 4 + 3] = v.w;
    }
    float4 acc[8];
#pragma unroll
    for (int q = 0; q < 8; q++) acc[q] = *(const float4*)&prm[q * 4];
#pragma unroll
    for (int k = 0; k < 32; k++) {
#pragma unroll
        for (int q = 0; q < 8; q++) {
            float4 w = *(const float4*)&W1s[k * 32 + q * 4];
            acc[q] = f4fma(hv[k], w, acc[q]);
        }
    }
    float o = prm[64];
#pragma unroll
    for (int q = 0; q < 8; q++) {
        o += leaky(acc[q].x) * prm[32 + q * 4 + 0];
        o += leaky(acc[q].y) * prm[32 + q * 4 + 1];
        o += leaky(acc[q].z) * prm[32 + q * 4 + 2];
        o += leaky(acc[q].w) * prm[32 + q * 4 + 3];
    }
    out[n] = o;
}

// ---------------- launch ----------------

extern "C" void kernel_launch(void* const* d_in, const int* in_sizes, int n_in,
                              void* d_out, int out_size, void* d_ws, size_t ws_size,
                              hipStream_t stream) {
    const float* x          = (const float*)d_in[0];
    const float* edge_attr  = (const float*)d_in[1];
    const int*   senders    = (const int*)d_in[2];
    const int*   receivers  = (const int*)d_in[3];
    const float* node_enc_W = (const float*)d_in[4];
    const float* node_enc_b = (const float*)d_in[5];
    const float* edge_enc_W = (const float*)d_in[6];
    const float* edge_enc_b = (const float*)d_in[7];
    const float* edge_W     = (const float*)d_in[8];
    const float* edge_b     = (const float*)d_in[9];
    const float* edge_ln_s  = (const float*)d_in[10];
    const float* edge_ln_b  = (const float*)d_in[11];
    const float* node_W     = (const float*)d_in[12];
    const float* node_b     = (const float*)d_in[13];
    const float* node_ln_s  = (const float*)d_in[14];
    const float* node_ln_b  = (const float*)d_in[15];
    const float* dec_W1     = (const float*)d_in[16];
    const float* dec_b1     = (const float*)d_in[17];
    const float* dec_W2     = (const float*)d_in[18];
    const float* dec_b2     = (const float*)d_in[19];
    float* out = (float*)d_out;

    char* ws = (char*)d_ws;
    size_t off = 0;
    auto alloc = [&](size_t bytes) -> void* {
        void* p = ws + off;
        off = (off + bytes + 255) & ~(size_t)255;
        return p;
    };
    float*        h         = (float*)alloc((size_t)N_NODES * 32 * 4);
    __bf16*       hbf       = (__bf16*)alloc((size_t)N_NODES * 32 * 2);
    __bf16*       e         = (__bf16*)alloc((size_t)N_EDGES * 32 * 2);
    int*          cnt       = (int*)alloc((size_t)N_NODES * 4);
    int*          row_start = (int*)alloc((size_t)(N_NODES + 1) * 4);
    int*          cursor    = (int*)alloc((size_t)N_NODES * 4);
    unsigned int* sr_p      = (unsigned int*)alloc((size_t)N_EDGES * 4);
    int*          partial   = (int*)alloc((size_t)SCAN_BLK * 4);
    (void)ws_size; (void)in_sizes; (void)n_in; (void)out_size;

    hipMemsetAsync(cnt, 0, (size_t)N_NODES * 4, stream);
    encode_nodes_kernel<<<(N_NODES + 255) / 256, 256, 0, stream>>>(x, node_enc_W, node_enc_b, h, hbf);
    count_kernel<<<(N_EDGES + 255) / 256, 256, 0, stream>>>(receivers, cnt);
    csr_reduce_kernel<<<SCAN_NBLK, SCAN_BLK, 0, stream>>>(cnt, partial);
    csr_scan_partials_kernel<<<1, SCAN_BLK, 0, stream>>>(partial, row_start);
    csr_apply_kernel<<<SCAN_NBLK, SCAN_BLK, 0, stream>>>(cnt, partial, row_start, cursor);
    scatter_encode_kernel<<<(N_EDGES + 255) / 256, 256, 0, stream>>>(
        edge_attr, senders, receivers, cursor, edge_enc_W, edge_enc_b, e, sr_p);

    int edge_blocks = (N_TILES + TILES_PER_BLOCK - 1) / TILES_PER_BLOCK;
    for (int s = 0; s < STEPS; s++) {
        edge_mfma_kernel<<<edge_blocks, 256, 0, stream>>>(
            e, hbf, sr_p,
            edge_W + (size_t)s * 96 * 32, edge_b + s * 32,
            edge_ln_s + s * 32, edge_ln_b + s * 32);
        node_kernel<<<(N_NODES + 255) / 256, 256, 0, stream>>>(
            h, hbf, e, row_start, node_W + (size_t)s * 64 * 32, node_b + s * 32,
            node_ln_s + s * 32, node_ln_b + s * 32);
    }
    decoder_kernel<<<(N_NODES + 255) / 256, 256, 0, stream>>>(h, dec_W1, dec_b1, dec_W2, dec_b2, out);
}